// Round 10
// baseline (78.568 us; speedup 1.0000x reference)
//
#include <hip/hip_runtime.h>
#include <hip/hip_bf16.h>

#define B_ROWS 8192
#define E_DIM  1024
#define MARGIN 0.2f

#define BM 256
#define BN 256          // output k-cols per block
#define BK 64           // e-reduction per K-tile
#define KSPLIT 2
#define KHALF (E_DIM / KSPLIT)   // 512
#define NT (KHALF / BK)          // 8 K-tiles per block

typedef __bf16 bf16x8 __attribute__((ext_vector_type(8)));
typedef float  f32x4  __attribute__((ext_vector_type(4)));

__device__ __forceinline__ void gload_lds16(const void* g, void* l) {
    __builtin_amdgcn_global_load_lds(
        (__attribute__((address_space(1))) void*)(g),
        (__attribute__((address_space(3))) void*)(l),
        16, 0, 0);
}

#define GATE6() do { asm volatile("s_waitcnt vmcnt(6)" ::: "memory"); \
                     __builtin_amdgcn_sched_barrier(0); } while (0)
#define GATE0() do { asm volatile("s_waitcnt vmcnt(0)" ::: "memory"); \
                     __builtin_amdgcn_sched_barrier(0); } while (0)
#define RBAR()  do { __builtin_amdgcn_s_barrier(); \
                     __builtin_amdgcn_sched_barrier(0); } while (0)
#define LGKM0() do { asm volatile("s_waitcnt lgkmcnt(0)" ::: "memory"); \
                     __builtin_amdgcn_sched_barrier(0); } while (0)

// Combined prep: blocks [0,4096) c = 0.4*m + 0.6*tr_m; [4096,5120) W -> Wt.
__global__ __launch_bounds__(256)
void prep_combo(const float* __restrict__ m, const float* __restrict__ trm,
                __bf16* __restrict__ c,
                const float* __restrict__ W, __bf16* __restrict__ Wt) {
    __shared__ float tile[32][33];
    if (blockIdx.x < 4096) {
        size_t i = ((size_t)blockIdx.x * blockDim.x + threadIdx.x) * 8;
        float4 m0 = *(const float4*)(m + i);
        float4 m1 = *(const float4*)(m + i + 4);
        float4 t0 = *(const float4*)(trm + i);
        float4 t1 = *(const float4*)(trm + i + 4);
        bf16x8 v;
        v[0] = (__bf16)(0.4f*m0.x + 0.6f*t0.x);
        v[1] = (__bf16)(0.4f*m0.y + 0.6f*t0.y);
        v[2] = (__bf16)(0.4f*m0.z + 0.6f*t0.z);
        v[3] = (__bf16)(0.4f*m0.w + 0.6f*t0.w);
        v[4] = (__bf16)(0.4f*m1.x + 0.6f*t1.x);
        v[5] = (__bf16)(0.4f*m1.y + 0.6f*t1.y);
        v[6] = (__bf16)(0.4f*m1.z + 0.6f*t1.z);
        v[7] = (__bf16)(0.4f*m1.w + 0.6f*t1.w);
        *(bf16x8*)(c + i) = v;
    } else {
        const int tb = blockIdx.x - 4096;
        const int bx = (tb & 31) * 32;          // n base
        const int by = (tb >> 5) * 32;          // e base
        const int tx = threadIdx.x & 31;
        const int ty0 = threadIdx.x >> 5;
#pragma unroll
        for (int r = 0; r < 32; r += 8)
            tile[r + ty0][tx] = W[(size_t)(by + r + ty0) * E_DIM + bx + tx];
        __syncthreads();
#pragma unroll
        for (int r = 0; r < 32; r += 8)
            Wt[(size_t)(bx + r + ty0) * E_DIM + by + tx] = (__bf16)tile[tx][r + ty0];
    }
}

// u = c @ Wt^T : 256x256 tile, BK=64, 8 waves (2Mx4N), split-K=2 -> 256 blocks.
// Pipeline: 16 x 4KiB LDS units per K-tile (A,B x quarter x k-half), staged 4
// units/phase ONE FULL TILE ahead of first use (uniform read-lag L=2 phases).
// Stage slots solved so every unit: readable >= its first read AND its (t+2)
// overwrite is strictly after its last read. Gate = counted vmcnt(6) (2 loads
// x 3 phases), one s_barrier/phase. Per phase: 4-8 ds_read_b128 (swizzled,
// conflict-free) | 2 gload_lds | lgkm0 | setprio + 16 MFMA | vmcnt | bar.
// Epilogue: rowwise dot with (Ais - Aem), atomicAdd into delta[].
__global__ __launch_bounds__(512, 2)
void gemm_dot(const __bf16* __restrict__ Cm, const __bf16* __restrict__ Wt,
              const float* __restrict__ Ais, const float* __restrict__ Aem,
              float* __restrict__ delta) {
    __shared__ __bf16 AU[2][4][2][2048];   // [buf][quarter][kk][64rows x 32k]
    __shared__ __bf16 BU[2][4][2][2048];   // 64 KiB + 64 KiB

    const int tid  = threadIdx.x;
    const int lane = tid & 63;
    const int lr   = lane & 15;
    const int hi   = lane >> 4;
    const int wave = tid >> 6;      // 0..7
    const int wr   = wave >> 2;     // 0..1 : M half (quarters 2wr, 2wr+1)
    const int wc   = wave & 3;      // 0..3 : N quarter (B unit wc)

    // 256 blocks = 8 xcd x (4 panels x 4 colb x 2 kh); per-XCD L2 ~4 MiB.
    const int bid   = blockIdx.x;
    const int xcd   = bid & 7;
    const int loc   = bid >> 3;                 // 0..31
    const int panel = xcd * 4 + (loc >> 3);     // 0..31
    const int sub   = loc & 7;
    const int rb    = panel * BM;
    const int cb    = (sub & 3) * BN;
    const int kbase = (sub >> 2) * KHALF;

    // stage one 4 KiB unit: 256 thread-slots x 16 B; wave-uniform LDS base.
    auto stageUnit = [&](int isA, int q, int kk, int T) {
        const int d   = (tid & 255) * 16;
        const int row = d >> 6;                                   // 64 B rows
        const int x   = (d & 63) ^ (((row >> 1) & 3) << 4);       // inv-swizzle
        const char* g = (const char*)(isA ? Cm : Wt) +
            ((size_t)((isA ? rb : cb) + q * 64 + row) * E_DIM +
             kbase + T * BK + kk * 32) * 2 + x;
        char* l = (char*)(isA ? &AU[T & 1][q][kk][0] : &BU[T & 1][q][kk][0]) + d;
        gload_lds16(g, l);
    };

    // stage-slot schedule (solved):
    // s0: A(0,k0) A(2,k0) A(0,k1) A(2,k1)
    // s1: B(0,k0) B(1,k0) A(1,k0) A(3,k0)
    // s2: B(2,k0) B(3,k0) B(0,k1) B(1,k1)
    // s3: A(1,k1) A(3,k1) B(2,k1) B(3,k1)
    // thread's 2 units: u = 2L + wr  (wave-uniform)
    auto stage_group = [&](int s, int T) {
        switch (s) {
        case 0: stageUnit(1, 2 * wr, 0, T);     stageUnit(1, 2 * wr, 1, T);     break;
        case 1: stageUnit(0, wr, 0, T);         stageUnit(1, 2 * wr + 1, 0, T); break;
        case 2: stageUnit(0, wr + 2, 0, T);     stageUnit(0, wr, 1, T);         break;
        default: stageUnit(1, 2 * wr + 1, 1, T); stageUnit(0, wr + 2, 1, T);    break;
        }
    };

    auto rdA = [&](int buf, int q, int kk, int ml) -> bf16x8 {
        const int row  = ml * 16 + lr;
        const int byte = row * 64 + ((hi * 16) ^ (((row >> 1) & 3) << 4));
        return *(const bf16x8*)((const char*)&AU[buf][q][kk][0] + byte);
    };
    auto rdB = [&](int buf, int kk, int ni) -> bf16x8 {
        const int row  = ni * 16 + lr;
        const int byte = row * 64 + ((hi * 16) ^ (((row >> 1) & 3) << 4));
        return *(const bf16x8*)((const char*)&BU[buf][wc][kk][0] + byte);
    };

    f32x4 acc[8][4] = {};
    bf16x8 b0[4], b1[4];

    // prologue: tile 0's 16 units (groups 0..3), 8 loads/thread
    stage_group(0, 0); stage_group(1, 0); stage_group(2, 0); stage_group(3, 0);

    for (int p = 0; p <= 4 * NT + 1; ++p) {
        // stage for tile (p>>2)+1 while reads/MFMA of tile (p-2)>>2 run
        if (p <= 4 * NT - 5) stage_group(p & 3, (p >> 2) + 1);

        const int e = p - 2;                  // uniform read-lag L=2
        if (e >= 0 && e < 4 * NT) {
            const int t = e >> 2, buf = t & 1, j = e & 3;
            bf16x8 a[4];
            switch (j) {
            case 0:   // (mh=0, kk=0) + load b0
#pragma unroll
                for (int ml = 0; ml < 4; ++ml) a[ml] = rdA(buf, 2 * wr, 0, ml);
#pragma unroll
                for (int ni = 0; ni < 4; ++ni) b0[ni] = rdB(buf, 0, ni);
                LGKM0();
                __builtin_amdgcn_s_setprio(1);
#pragma unroll
                for (int ml = 0; ml < 4; ++ml)
#pragma unroll
                    for (int ni = 0; ni < 4; ++ni)
                        acc[ml][ni] = __builtin_amdgcn_mfma_f32_16x16x32_bf16(
                            a[ml], b0[ni], acc[ml][ni], 0, 0, 0);
                __builtin_amdgcn_s_setprio(0);
                break;
            case 1:   // (mh=0, kk=1) + load b1
#pragma unroll
                for (int ml = 0; ml < 4; ++ml) a[ml] = rdA(buf, 2 * wr, 1, ml);
#pragma unroll
                for (int ni = 0; ni < 4; ++ni) b1[ni] = rdB(buf, 1, ni);
                LGKM0();
                __builtin_amdgcn_s_setprio(1);
#pragma unroll
                for (int ml = 0; ml < 4; ++ml)
#pragma unroll
                    for (int ni = 0; ni < 4; ++ni)
                        acc[ml][ni] = __builtin_amdgcn_mfma_f32_16x16x32_bf16(
                            a[ml], b1[ni], acc[ml][ni], 0, 0, 0);
                __builtin_amdgcn_s_setprio(0);
                break;
            case 2:   // (mh=1, kk=0), reuse b0
#pragma unroll
                for (int ml = 0; ml < 4; ++ml) a[ml] = rdA(buf, 2 * wr + 1, 0, ml);
                LGKM0();
                __builtin_amdgcn_s_setprio(1);
#pragma unroll
                for (int ml = 0; ml < 4; ++ml)
#pragma unroll
                    for (int ni = 0; ni < 4; ++ni)
                        acc[4 + ml][ni] = __builtin_amdgcn_mfma_f32_16x16x32_bf16(
                            a[ml], b0[ni], acc[4 + ml][ni], 0, 0, 0);
                __builtin_amdgcn_s_setprio(0);
                break;
            default:  // (mh=1, kk=1), reuse b1
#pragma unroll
                for (int ml = 0; ml < 4; ++ml) a[ml] = rdA(buf, 2 * wr + 1, 1, ml);
                LGKM0();
                __builtin_amdgcn_s_setprio(1);
#pragma unroll
                for (int ml = 0; ml < 4; ++ml)
#pragma unroll
                    for (int ni = 0; ni < 4; ++ni)
                        acc[4 + ml][ni] = __builtin_amdgcn_mfma_f32_16x16x32_bf16(
                            a[ml], b1[ni], acc[4 + ml][ni], 0, 0, 0);
                __builtin_amdgcn_s_setprio(0);
                break;
            }
        }

        if (p <= 4 * NT - 5) { GATE6(); } else { GATE0(); }
        RBAR();
    }

    // epilogue: delta[r] += sum_k u[r][k] * (Ais - Aem)[r][k]
    // C/D layout: col = lane&15, row = (lane>>4)*4 + reg
    const int colbase = cb + wc * 64 + lr;
#pragma unroll
    for (int mh = 0; mh < 2; ++mh) {
#pragma unroll
        for (int ml = 0; ml < 4; ++ml) {
#pragma unroll
            for (int jj = 0; jj < 4; ++jj) {
                const int r = rb + (2 * wr + mh) * 64 + ml * 16 + hi * 4 + jj;
                float v = 0.f;
#pragma unroll
                for (int ni = 0; ni < 4; ++ni) {
                    const size_t idx = (size_t)r * E_DIM + colbase + ni * 16;
                    v += acc[mh * 4 + ml][ni][jj] * (Ais[idx] - Aem[idx]);
                }
                v += __shfl_xor(v, 1);
                v += __shfl_xor(v, 2);
                v += __shfl_xor(v, 4);
                v += __shfl_xor(v, 8);
                if (lr == 0) atomicAdd(&delta[r], v);
            }
        }
    }
}

__global__ void hinge_sum(const float* __restrict__ delta, float* __restrict__ out) {
    float s = 0.f;
    for (int i = threadIdx.x; i < B_ROWS; i += 256)
        s += fmaxf(MARGIN + delta[i], 0.f);
#pragma unroll
    for (int off = 32; off > 0; off >>= 1) s += __shfl_down(s, off);
    __shared__ float wsum[4];
    int lane = threadIdx.x & 63, w = threadIdx.x >> 6;
    if (lane == 0) wsum[w] = s;
    __syncthreads();
    if (threadIdx.x == 0) out[0] = wsum[0] + wsum[1] + wsum[2] + wsum[3];
}

extern "C" void kernel_launch(void* const* d_in, const int* in_sizes, int n_in,
                              void* d_out, int out_size, void* d_ws, size_t ws_size,
                              hipStream_t stream) {
    const float* A_is = (const float*)d_in[0];
    const float* A_em = (const float*)d_in[1];
    const float* m    = (const float*)d_in[2];
    const float* tr_m = (const float*)d_in[3];
    const float* W    = (const float*)d_in[4];
    // d_in[5] = b : cancels in diag_is - diag_em, unused.
    float* out = (float*)d_out;

    char* ws = (char*)d_ws;
    __bf16* c     = (__bf16*)ws;                              // 16 MiB
    __bf16* wt    = (__bf16*)(ws + (size_t)16 * 1024 * 1024); //  2 MiB
    float*  delta = (float*) (ws + (size_t)18 * 1024 * 1024); // 32 KiB

    hipMemsetAsync(delta, 0, B_ROWS * sizeof(float), stream);
    prep_combo<<<5120, 256, 0, stream>>>(m, tr_m, c, W, wt);
    gemm_dot<<<256, 512, 0, stream>>>(c, wt, A_is, A_em, delta);
    hinge_sum<<<1, 256, 0, stream>>>(delta, out);
}

// Round 11
// 78.318 us; speedup vs baseline: 1.0032x; 1.0032x over previous
//
#include <hip/hip_runtime.h>
#include <hip/hip_bf16.h>

#define B_ROWS 8192
#define E_DIM  1024
#define MARGIN 0.2f

#define BM 128
#define BN 128
#define BK 32
#define NSTEPS (E_DIM / BK)   // 32

typedef __bf16 bf16x8 __attribute__((ext_vector_type(8)));
typedef float  f32x4  __attribute__((ext_vector_type(4)));

__device__ __forceinline__ void gload_lds16(const void* g, void* l) {
    __builtin_amdgcn_global_load_lds(
        (__attribute__((address_space(1))) void*)(g),
        (__attribute__((address_space(3))) void*)(l),
        16, 0, 0);
}

// blocks [0,1024): Wt[n][e] = bf16(W[e][n]); blocks [1024,1056): zero delta.
__global__ __launch_bounds__(256)
void trans_zero(const float* __restrict__ W, __bf16* __restrict__ Wt,
                float* __restrict__ delta) {
    if (blockIdx.x < 1024) {
        __shared__ float tile[32][33];
        const int tb = blockIdx.x;
        const int bx = (tb & 31) * 32;          // n base
        const int by = (tb >> 5) * 32;          // e base
        const int tx = threadIdx.x & 31;
        const int ty0 = threadIdx.x >> 5;       // 8 rows/thread
#pragma unroll
        for (int r = 0; r < 32; r += 8)
            tile[r + ty0][tx] = W[(size_t)(by + r + ty0) * E_DIM + bx + tx];
        __syncthreads();
#pragma unroll
        for (int r = 0; r < 32; r += 8)
            Wt[(size_t)(bx + r + ty0) * E_DIM + by + tx] = (__bf16)tile[tx][r + ty0];
    } else {
        delta[(blockIdx.x - 1024) * 256 + threadIdx.x] = 0.f;
    }
}

// Fully-fused GEMM: A = c = 0.4*m + 0.6*tr_m built IN-KERNEL. Raw fp32 m and
// tr_m tiles are staged via global_load_lds (un-sinkable, unlike the R2/R3
// reg-staging that the compiler defeated); the bf16 A-frag is combined in
// registers after ds_read. m/trm LDS tiles have 128 B rows -> true 16-way
// bank conflict, fixed with the R5-verified both-sides XOR swizzle
// (byte ^= (row&7)<<4 on the global source k-offset AND on the read offset;
// LDS dest stays linear per rule #21). B (Wt bf16) staged linear as before.
// Plain 2-phase loop, one __syncthreads per K-step, no asm gates (m141),
// no setprio (m190). Epilogue: rowwise dot with (Ais - Aem) -> atomicAdd.
__global__ __launch_bounds__(256)
void gemm_fused(const float* __restrict__ mIn, const float* __restrict__ trmIn,
                const __bf16* __restrict__ Wt,
                const float* __restrict__ Ais, const float* __restrict__ Aem,
                float* __restrict__ delta) {
    __shared__ float  Ms[2][BM * BK];    // 2 x 16 KiB fp32 m tile (swizzled)
    __shared__ float  Ts[2][BM * BK];    // 2 x 16 KiB fp32 tr_m tile (swizzled)
    __shared__ __bf16 Bs[2][BN * BK];    // 2 x  8 KiB bf16 Wt tile (linear)

    const int tid  = threadIdx.x;
    const int lane = tid & 63;
    const int wave = tid >> 6;
    const int lr   = lane & 15;
    const int hi   = lane >> 4;
    const int wr   = wave >> 1, wc = wave & 1;

    // XCD swizzle: xcd owns 8 row-panels x all 8 colb -> each panel's
    // m+tr_m (1 MiB) is HBM/L3-read once, L2-hit for the other 7 col-blocks.
    const int bid = blockIdx.x;
    const int xcd = bid & 7;
    const int q   = bid >> 3;            // 0..63
    const int rb  = (xcd * 8 + (q >> 3)) * BM;
    const int cb  = (q & 7) * BN;

    auto stage = [&](int buf, int k0) {
        // m / tr_m fp32 tiles: 16 KiB each, 128 B rows, inverse-swizzled src
#pragma unroll
        for (int i = 0; i < 4; ++i) {
            const int d   = i * 4096 + tid * 16;
            const int row = d >> 7;
            const int cbi = (d & 127) ^ ((row & 7) << 4);
            const size_t g = ((size_t)(rb + row) * E_DIM + k0) * 4 + cbi;
            gload_lds16((const char*)mIn + g,   (char*)(&Ms[buf][0]) + d);
            gload_lds16((const char*)trmIn + g, (char*)(&Ts[buf][0]) + d);
        }
        // Wt bf16 tile: 8 KiB, 64 B rows, linear
#pragma unroll
        for (int i = 0; i < 2; ++i) {
            const int d   = i * 4096 + tid * 16;
            const int row = d >> 6;
            const int kb  = d & 63;
            gload_lds16((const char*)Wt + ((size_t)(cb + row) * E_DIM + k0) * 2 + kb,
                        (char*)(&Bs[buf][0]) + d);
        }
    };

    f32x4 acc[4][4] = {};

    stage(0, 0);
    __syncthreads();

    int cur = 0;
    for (int t = 0; t < NSTEPS; ++t) {
        if (t + 1 < NSTEPS) stage(cur ^ 1, (t + 1) * BK);

        // build A-frags in-register: a = bf16(0.4*m + 0.6*trm)
        const char* mb = (const char*)&Ms[cur][0];
        const char* tb = (const char*)&Ts[cur][0];
        bf16x8 a[4], b[4];
#pragma unroll
        for (int mi = 0; mi < 4; ++mi) {
            const int row = wr * 64 + mi * 16 + lr;
            const int s   = (row & 7) << 4;
            const int o0  = row * 128 + ((hi * 32) ^ s);
            const int o1  = row * 128 + ((hi * 32 + 16) ^ s);
            const f32x4 m0 = *(const f32x4*)(mb + o0);
            const f32x4 m1 = *(const f32x4*)(mb + o1);
            const f32x4 t0 = *(const f32x4*)(tb + o0);
            const f32x4 t1 = *(const f32x4*)(tb + o1);
#pragma unroll
            for (int j = 0; j < 4; ++j) {
                a[mi][j]     = (__bf16)(0.4f * m0[j] + 0.6f * t0[j]);
                a[mi][4 + j] = (__bf16)(0.4f * m1[j] + 0.6f * t1[j]);
            }
        }
#pragma unroll
        for (int ni = 0; ni < 4; ++ni)
            b[ni] = *(const bf16x8*)(&Bs[cur][(wc * 64 + ni * 16 + lr) * BK + hi * 8]);

#pragma unroll
        for (int mi = 0; mi < 4; ++mi)
#pragma unroll
            for (int ni = 0; ni < 4; ++ni)
                acc[mi][ni] = __builtin_amdgcn_mfma_f32_16x16x32_bf16(
                    a[mi], b[ni], acc[mi][ni], 0, 0, 0);

        __syncthreads();
        cur ^= 1;
    }

    // epilogue: delta[r] += sum_col u[r][col] * (Ais - Aem)[r][col]
    // C/D layout (16x16x32): col = lane&15, row = (lane>>4)*4 + reg
    const int colbase = cb + wc * 64 + lr;
    const int rowbase = rb + wr * 64 + hi * 4;
#pragma unroll
    for (int mi = 0; mi < 4; ++mi) {
#pragma unroll
        for (int jj = 0; jj < 4; ++jj) {
            const int r = rowbase + mi * 16 + jj;
            float v = 0.f;
#pragma unroll
            for (int ni = 0; ni < 4; ++ni) {
                const size_t idx = (size_t)r * E_DIM + colbase + ni * 16;
                v += acc[mi][ni][jj] * (Ais[idx] - Aem[idx]);
            }
            v += __shfl_xor(v, 1);
            v += __shfl_xor(v, 2);
            v += __shfl_xor(v, 4);
            v += __shfl_xor(v, 8);
            if (lr == 0) atomicAdd(&delta[r], v);
        }
    }
}

__global__ void hinge_sum(const float* __restrict__ delta, float* __restrict__ out) {
    float s = 0.f;
    for (int i = threadIdx.x; i < B_ROWS; i += 256)
        s += fmaxf(MARGIN + delta[i], 0.f);
#pragma unroll
    for (int off = 32; off > 0; off >>= 1) s += __shfl_down(s, off);
    __shared__ float wsum[4];
    int lane = threadIdx.x & 63, w = threadIdx.x >> 6;
    if (lane == 0) wsum[w] = s;
    __syncthreads();
    if (threadIdx.x == 0) out[0] = wsum[0] + wsum[1] + wsum[2] + wsum[3];
}

extern "C" void kernel_launch(void* const* d_in, const int* in_sizes, int n_in,
                              void* d_out, int out_size, void* d_ws, size_t ws_size,
                              hipStream_t stream) {
    const float* A_is = (const float*)d_in[0];
    const float* A_em = (const float*)d_in[1];
    const float* m    = (const float*)d_in[2];
    const float* tr_m = (const float*)d_in[3];
    const float* W    = (const float*)d_in[4];
    // d_in[5] = b : cancels in diag_is - diag_em, unused.
    float* out = (float*)d_out;

    char* ws = (char*)d_ws;
    __bf16* wt    = (__bf16*)ws;                             // 2 MiB
    float*  delta = (float*)(ws + (size_t)2 * 1024 * 1024);  // 32 KiB

    trans_zero<<<1056, 256, 0, stream>>>(W, wt, delta);
    gemm_fused<<<512, 256, 0, stream>>>(m, tr_m, wt, A_is, A_em, delta);
    hinge_sum<<<1, 256, 0, stream>>>(delta, out);
}